// Round 16
// baseline (1572.715 us; speedup 1.0000x reference)
//
#include <hip/hip_runtime.h>

#define NP 50000
#define NL 10000
#define PLEN 5
#define NE (NP * PLEN)
#define DD 32
#define RUU 256
#define TITERS 8
#define PPB 16   /* paths per block (4 per wave) */
#define LPB 4    /* links per block (1 per wave) */
#define RPB 32   /* paths per readout block */

__device__ __forceinline__ float sigmoidf_(float a) {
    return 1.0f / (1.0f + __expf(-a));
}
__device__ __forceinline__ float tanhf_(float a) {
    a = fminf(fmaxf(a, -15.0f), 15.0f);
    float t = __expf(2.0f * a);
    return (t - 1.0f) / (t + 1.0f);
}

__global__ __launch_bounds__(256) void k_init(
    const float* __restrict__ traffic, const float* __restrict__ packets,
    const float* __restrict__ tdp, const float* __restrict__ capacity,
    float* __restrict__ path_state, float* __restrict__ link_state,
    int* __restrict__ lens, int* __restrict__ cnt) {
    int i = blockIdx.x * 256 + threadIdx.x;
    if (i < NP) {
        float v[DD];
        v[0] = traffic[i];
        v[1] = packets[i];
#pragma unroll
        for (int k = 0; k < 12; k++) v[2 + k] = tdp[i * 12 + k];
#pragma unroll
        for (int k = 14; k < DD; k++) v[k] = 0.0f;
#pragma unroll
        for (int k = 0; k < DD; k++) path_state[i * DD + k] = v[k];
        lens[i] = 0;
    }
    if (i < NL) {
        link_state[i * DD] = capacity[i];
#pragma unroll
        for (int k = 1; k < DD; k++) link_state[i * DD + k] = 0.0f;
        cnt[i] = 0;
    }
}

__global__ __launch_bounds__(256) void k_lens(const int* __restrict__ path_ids,
                                              const int* __restrict__ seq_path,
                                              int* __restrict__ lens) {
    int e = blockIdx.x * 256 + threadIdx.x;
    if (e < NE) atomicMax(&lens[path_ids[e]], seq_path[e] + 1);
}

__global__ __launch_bounds__(256) void k_csr_count(const int* __restrict__ seq_links,
                                                   int* __restrict__ cnt) {
    int e = blockIdx.x * 256 + threadIdx.x;
    if (e < NE) atomicAdd(&cnt[seq_links[e]], 1);
}

__global__ __launch_bounds__(256) void k_csr_scan(const int* __restrict__ cnt,
                                                  int* __restrict__ offs,
                                                  int* __restrict__ cursor) {
    __shared__ int ssum[256];
    const int tid = threadIdx.x;
    const int CH = 40;
    int base = tid * CH;
    int s = 0;
    for (int i = 0; i < CH; i++) {
        int idx = base + i;
        s += (idx < NL) ? cnt[idx] : 0;
    }
    ssum[tid] = s;
    __syncthreads();
    for (int off = 1; off < 256; off <<= 1) {
        int t = (tid >= off) ? ssum[tid - off] : 0;
        __syncthreads();
        ssum[tid] += t;
        __syncthreads();
    }
    int run = ssum[tid] - s;
    for (int i = 0; i < CH; i++) {
        int idx = base + i;
        if (idx < NL) {
            offs[idx] = run;
            cursor[idx] = run;
            run += cnt[idx];
        }
    }
    if (tid == 0) offs[NL] = ssum[255];
}

__global__ __launch_bounds__(256) void k_csr_fill(const int* __restrict__ seq_links,
                                                  const int* __restrict__ path_to_link,
                                                  int* __restrict__ cursor,
                                                  int* __restrict__ csr_pids) {
    int e = blockIdx.x * 256 + threadIdx.x;
    if (e < NE) {
        int l = seq_links[e];
        int slot = atomicAdd(&cursor[l], 1);
        csr_pids[slot] = path_to_link[e];
    }
}

__global__ __launch_bounds__(256) void k_w2t(const float* __restrict__ W2,
                                             float* __restrict__ W2t) {
    int j = blockIdx.x, k = threadIdx.x;
    W2t[k * RUU + j] = W2[j * RUU + k];
}

// Path GRU, phase-split. Phase 1: pipelined gather + Wi (round-12 proven).
// Phase 2: recurrence with Wh, 2 paths interleaved (round-10 proven).
__global__ __launch_bounds__(256, 4) void k_gru_paths(
    const float* __restrict__ link_state, float* __restrict__ path_state,
    const int* __restrict__ link_to_path, const int* __restrict__ lens,
    const float* __restrict__ Wi, const float* __restrict__ Wh,
    const float* __restrict__ bi, const float* __restrict__ bh) {
    __shared__ float gi[PPB * PLEN * 96];   // 30720 B
    __shared__ float hbuf[4][2][DD];        // 1 KB
    const int tid = threadIdx.x;
    const int wave = tid >> 6;
    const int lane = tid & 63;
    const int d = lane & 31;
    const int half = lane >> 5;
    const int pl0 = wave * 4;
    const int pbase = blockIdx.x * PPB;

    float w[3][16];
    // ---- Phase 1: input transform with Wi, pipelined gather ----
#pragma unroll
    for (int g = 0; g < 3; g++) {
        const float* wp = &Wi[(g * 32 + d) * 32 + half * 16];
#pragma unroll
        for (int c = 0; c < 4; c++) *(float4*)&w[g][c * 4] = *(const float4*)&wp[c * 4];
    }
#pragma unroll
    for (int g = 0; g < 3; g++)
#pragma unroll
        for (int k = 0; k < 16; k++) asm volatile("" : "+v"(w[g][k]));
    {
        const float b0 = bi[d], b1_ = bi[d + 32], b2_ = bi[d + 64];
        int lia[4 * PLEN];
#pragma unroll
        for (int j = 0; j < 4; j++) {
            const int p = pbase + pl0 + j;
#pragma unroll
            for (int s = 0; s < PLEN; s++) lia[j * PLEN + s] = link_to_path[p * PLEN + s];
        }
        float xk[16];
#pragma unroll
        for (int c = 0; c < 4; c++)
            *(float4*)&xk[c * 4] =
                *(const float4*)&link_state[lia[0] * DD + half * 16 + c * 4];
#pragma unroll
        for (int u = 0; u < 20; u++) {
            float xn[16];
            if (u + 1 < 20) {
#pragma unroll
                for (int c = 0; c < 4; c++)
                    *(float4*)&xn[c * 4] =
                        *(const float4*)&link_state[lia[u + 1] * DD + half * 16 + c * 4];
            }
            float s0 = 0.f, s1 = 0.f, s2 = 0.f;
#pragma unroll
            for (int k = 0; k < 16; k++) {
                s0 = fmaf(xk[k], w[0][k], s0);
                s1 = fmaf(xk[k], w[1][k], s1);
                s2 = fmaf(xk[k], w[2][k], s2);
            }
            s0 += __shfl_xor(s0, 32);
            s1 += __shfl_xor(s1, 32);
            s2 += __shfl_xor(s2, 32);
            float* gp = &gi[(pl0 + (u / 5)) * (PLEN * 96) + (u % 5) * 96];
            gp[d]      = s0 + b0;
            gp[d + 32] = s1 + b1_;
            gp[d + 64] = s2 + b2_;
            if (u + 1 < 20) {
#pragma unroll
                for (int k = 0; k < 16; k++) xk[k] = xn[k];
            }
        }
    }
    __syncthreads();   // phase fence

    // ---- Phase 2: recurrence with Wh (register reuse), 2 paths in flight ----
#pragma unroll
    for (int g = 0; g < 3; g++) {
        const float* wp = &Wh[(g * 32 + d) * 32 + half * 16];
#pragma unroll
        for (int c = 0; c < 4; c++) *(float4*)&w[g][c * 4] = *(const float4*)&wp[c * 4];
    }
#pragma unroll
    for (int g = 0; g < 3; g++)
#pragma unroll
        for (int k = 0; k < 16; k++) asm volatile("" : "+v"(w[g][k]));
    const float bh0 = bh[d], bh1 = bh[d + 32], bh2 = bh[d + 64];

    for (int j = 0; j < 4; j += 2) {
        const int pA = pbase + pl0 + j;
        const int pB = pA + 1;
        const int lenA = lens[pA], lenB = lens[pB];
        float hdA = path_state[pA * DD + d];
        float hdB = path_state[pB * DD + d];
        float hkA[16], hkB[16];
#pragma unroll
        for (int c = 0; c < 4; c++) {
            *(float4*)&hkA[c * 4] = *(const float4*)&path_state[pA * DD + half * 16 + c * 4];
            *(float4*)&hkB[c * 4] = *(const float4*)&path_state[pB * DD + half * 16 + c * 4];
        }
#pragma unroll
        for (int st = 0; st < PLEN; st++) {
            float hrA = 0.f, hzA = 0.f, hnA = 0.f;
            float hrB = 0.f, hzB = 0.f, hnB = 0.f;
#pragma unroll
            for (int k = 0; k < 16; k++) {
                hrA = fmaf(hkA[k], w[0][k], hrA);
                hzA = fmaf(hkA[k], w[1][k], hzA);
                hnA = fmaf(hkA[k], w[2][k], hnA);
                hrB = fmaf(hkB[k], w[0][k], hrB);
                hzB = fmaf(hkB[k], w[1][k], hzB);
                hnB = fmaf(hkB[k], w[2][k], hnB);
            }
            hrA += __shfl_xor(hrA, 32);
            hzA += __shfl_xor(hzA, 32);
            hnA += __shfl_xor(hnA, 32);
            hrB += __shfl_xor(hrB, 32);
            hzB += __shfl_xor(hzB, 32);
            hnB += __shfl_xor(hnB, 32);
            const float* gpA = &gi[((pl0 + j) * PLEN + st) * 96];
            const float* gpB = &gi[((pl0 + j + 1) * PLEN + st) * 96];
            float rA = sigmoidf_(gpA[d] + hrA + bh0);
            float zA = sigmoidf_(gpA[d + 32] + hzA + bh1);
            float nA = tanhf_(gpA[d + 64] + rA * (hnA + bh2));
            float rB = sigmoidf_(gpB[d] + hrB + bh0);
            float zB = sigmoidf_(gpB[d + 32] + hzB + bh1);
            float nB = tanhf_(gpB[d + 64] + rB * (hnB + bh2));
            float hnewA = (1.0f - zA) * nA + zA * hdA;
            float hnewB = (1.0f - zB) * nB + zB * hdB;
            hdA = (st < lenA) ? hnewA : hdA;
            hdB = (st < lenB) ? hnewB : hdB;
            hbuf[wave][0][d] = hdA;   // unconditional, identical bits both halves
            hbuf[wave][1][d] = hdB;
#pragma unroll
            for (int c = 0; c < 4; c++) {
                *(float4*)&hkA[c * 4] = *(const float4*)&hbuf[wave][0][half * 16 + c * 4];
                *(float4*)&hkB[c * 4] = *(const float4*)&hbuf[wave][1][half * 16 + c * 4];
            }
        }
        if (half == 0) {
            path_state[pA * DD + d] = hdA;
            path_state[pB * DD + d] = hdB;
        }
    }
}

// Link update, 3-phase; wave = 1 link; 4-deep pipelined gather (round-12).
__global__ __launch_bounds__(256, 4) void k_links(
    const float* __restrict__ path_state, float* __restrict__ link_state,
    const int* __restrict__ offs, const int* __restrict__ csr_pids,
    const float* __restrict__ Wi, const float* __restrict__ Wh,
    const float* __restrict__ bi, const float* __restrict__ bh) {
    __shared__ float xsum[4][DD];     // 512 B
    __shared__ float gil[4][96];      // 1536 B
    const int tid = threadIdx.x;
    const int wave = tid >> 6;
    const int lane = tid & 63;
    const int d = lane & 31;
    const int half = lane >> 5;
    const int l = blockIdx.x * LPB + wave;

    float w[3][16];
#pragma unroll
    for (int g = 0; g < 3; g++) {
        const float* wp = &Wi[(g * 32 + d) * 32 + half * 16];
#pragma unroll
        for (int c = 0; c < 4; c++) *(float4*)&w[g][c * 4] = *(const float4*)&wp[c * 4];
    }
#pragma unroll
    for (int g = 0; g < 3; g++)
#pragma unroll
        for (int k = 0; k < 16; k++) asm volatile("" : "+v"(w[g][k]));

    const int beg = offs[l], end = offs[l + 1];
    float a0 = 0.f, a1 = 0.f, a2 = 0.f, a3 = 0.f;
    int t = beg + half;
    for (; t + 6 < end; t += 8) {
        int q0 = csr_pids[t];
        int q1 = csr_pids[t + 2];
        int q2 = csr_pids[t + 4];
        int q3 = csr_pids[t + 6];
        a0 += path_state[q0 * DD + d];
        a1 += path_state[q1 * DD + d];
        a2 += path_state[q2 * DD + d];
        a3 += path_state[q3 * DD + d];
    }
    for (; t < end; t += 2) a0 += path_state[csr_pids[t] * DD + d];
    float xv = (a0 + a1) + (a2 + a3);
    xv += __shfl_xor(xv, 32);
    xsum[wave][d] = xv;
    __syncthreads();

    {
        const float b0 = bi[d], b1_ = bi[d + 32], b2_ = bi[d + 64];
        float xk[16];
#pragma unroll
        for (int c = 0; c < 4; c++)
            *(float4*)&xk[c * 4] = *(const float4*)&xsum[wave][half * 16 + c * 4];
        float s0 = 0.f, s1 = 0.f, s2 = 0.f;
#pragma unroll
        for (int k = 0; k < 16; k++) {
            s0 = fmaf(xk[k], w[0][k], s0);
            s1 = fmaf(xk[k], w[1][k], s1);
            s2 = fmaf(xk[k], w[2][k], s2);
        }
        s0 += __shfl_xor(s0, 32);
        s1 += __shfl_xor(s1, 32);
        s2 += __shfl_xor(s2, 32);
        gil[wave][d]      = s0 + b0;
        gil[wave][d + 32] = s1 + b1_;
        gil[wave][d + 64] = s2 + b2_;
    }
    __syncthreads();

#pragma unroll
    for (int g = 0; g < 3; g++) {
        const float* wp = &Wh[(g * 32 + d) * 32 + half * 16];
#pragma unroll
        for (int c = 0; c < 4; c++) *(float4*)&w[g][c * 4] = *(const float4*)&wp[c * 4];
    }
#pragma unroll
    for (int g = 0; g < 3; g++)
#pragma unroll
        for (int k = 0; k < 16; k++) asm volatile("" : "+v"(w[g][k]));
    const float bh0 = bh[d], bh1 = bh[d + 32], bh2 = bh[d + 64];
    {
        float hd = link_state[l * DD + d];
        float hk[16];
#pragma unroll
        for (int c = 0; c < 4; c++)
            *(float4*)&hk[c * 4] = *(const float4*)&link_state[l * DD + half * 16 + c * 4];
        float hr = 0.f, hz = 0.f, hn = 0.f;
#pragma unroll
        for (int k = 0; k < 16; k++) {
            hr = fmaf(hk[k], w[0][k], hr);
            hz = fmaf(hk[k], w[1][k], hz);
            hn = fmaf(hk[k], w[2][k], hn);
        }
        hr += __shfl_xor(hr, 32);
        hz += __shfl_xor(hz, 32);
        hn += __shfl_xor(hn, 32);
        float gir = gil[wave][d], giz = gil[wave][d + 32], gin = gil[wave][d + 64];
        float r = sigmoidf_(gir + hr + bh0);
        float z = sigmoidf_(giz + hz + bh1);
        float n = tanhf_(gin + r * (hn + bh2));
        float hnew = (1.0f - z) * n + z * hd;
        if (half == 0) link_state[l * DD + d] = hnew;
    }
}

// Readout: 32 paths/block, LDS 32KB. Thread tile 4x8 with STATIC 2-deep
// W2t register pipeline (named wc/wn arrays, compile-time indices only).
__global__ __launch_bounds__(256, 4) void k_readout(
    const float* __restrict__ path_state, float* __restrict__ out,
    const float* __restrict__ W1, const float* __restrict__ b1,
    const float* __restrict__ W2t, const float* __restrict__ b2,
    const float* __restrict__ W3, const float* __restrict__ b3) {
    __shared__ float sr1[RPB * RUU];     // 32 KB
    const int tid = threadIdx.x;
    const int p0 = blockIdx.x * RPB;

    float w1r[DD];
#pragma unroll
    for (int c = 0; c < 8; c++)
        *(float4*)&w1r[c * 4] = *(const float4*)&W1[tid * DD + c * 4];
    float bb1 = b1[tid];

#pragma unroll 2
    for (int m = 0; m < RPB; m++) {
        int p = p0 + m;
        if (p >= NP) p = NP - 1;
        const float4* xr = (const float4*)&path_state[(size_t)p * DD];
        float acc = bb1;
#pragma unroll
        for (int c = 0; c < 8; c++) {
            float4 xv = xr[c];
            acc = fmaf(xv.x, w1r[c * 4 + 0], fmaf(xv.y, w1r[c * 4 + 1],
                  fmaf(xv.z, w1r[c * 4 + 2], fmaf(xv.w, w1r[c * 4 + 3], acc))));
        }
        sr1[m * RUU + tid] = fmaxf(acc, 0.0f);
    }
    __syncthreads();

    const int pig = tid >> 5;   // 8 groups x 4 paths
    const int jg  = tid & 31;   // 32 groups x 8 cols
    float accs[4][8];
#pragma unroll
    for (int jj = 0; jj < 8; jj++) {
        float bv = b2[jg * 8 + jj];
#pragma unroll
        for (int pp = 0; pp < 4; pp++) accs[pp][jj] = bv;
    }

#define LOADW(dst, kbase)                                                      \
    {                                                                          \
        _Pragma("unroll") for (int kk = 0; kk < 4; kk++) {                     \
            dst[kk][0] = *(const float4*)&W2t[(size_t)((kbase) + kk) * RUU + jg * 8];     \
            dst[kk][1] = *(const float4*)&W2t[(size_t)((kbase) + kk) * RUU + jg * 8 + 4]; \
        }                                                                      \
    }
#define FMABLK(wv, kbase)                                                      \
    {                                                                          \
        float a[4][4];                                                         \
        _Pragma("unroll") for (int pp = 0; pp < 4; pp++)                       \
            *(float4*)&a[pp][0] = *(const float4*)&sr1[(pig * 4 + pp) * RUU + (kbase)]; \
        _Pragma("unroll") for (int kk = 0; kk < 4; kk++) {                     \
            float4 w0 = wv[kk][0];                                             \
            float4 w1_ = wv[kk][1];                                            \
            _Pragma("unroll") for (int pp = 0; pp < 4; pp++) {                 \
                float av = a[pp][kk];                                          \
                accs[pp][0] = fmaf(av, w0.x, accs[pp][0]);                     \
                accs[pp][1] = fmaf(av, w0.y, accs[pp][1]);                     \
                accs[pp][2] = fmaf(av, w0.z, accs[pp][2]);                     \
                accs[pp][3] = fmaf(av, w0.w, accs[pp][3]);                     \
                accs[pp][4] = fmaf(av, w1_.x, accs[pp][4]);                    \
                accs[pp][5] = fmaf(av, w1_.y, accs[pp][5]);                    \
                accs[pp][6] = fmaf(av, w1_.z, accs[pp][6]);                    \
                accs[pp][7] = fmaf(av, w1_.w, accs[pp][7]);                    \
            }                                                                  \
        }                                                                      \
    }

    float4 wc[4][2], wn[4][2];
    LOADW(wc, 0);
    for (int k4 = 0; k4 < 64; k4 += 2) {
        LOADW(wn, (k4 + 1) * 4);     // prefetch odd slab
        FMABLK(wc, k4 * 4);          // compute even slab
        if (k4 + 2 < 64) LOADW(wc, (k4 + 2) * 4);   // prefetch next even
        FMABLK(wn, (k4 + 1) * 4);    // compute odd slab
    }
#undef LOADW
#undef FMABLK

    float w3r[8];
#pragma unroll
    for (int c = 0; c < 2; c++)
        *(float4*)&w3r[c * 4] = *(const float4*)&W3[jg * 8 + c * 4];
    float val[4];
#pragma unroll
    for (int pp = 0; pp < 4; pp++) {
        float v = 0.f;
#pragma unroll
        for (int jj = 0; jj < 8; jj++) v = fmaf(w3r[jj], fmaxf(accs[pp][jj], 0.f), v);
        val[pp] = v;
    }
#pragma unroll
    for (int m = 1; m < 32; m <<= 1)
#pragma unroll
        for (int pp = 0; pp < 4; pp++) val[pp] += __shfl_xor(val[pp], m);
    if (jg == 0) {
        float b3v = b3[0];
#pragma unroll
        for (int pp = 0; pp < 4; pp++) {
            int p = p0 + pig * 4 + pp;
            if (p < NP) out[p] = val[pp] + b3v;
        }
    }
}

extern "C" void kernel_launch(void* const* d_in, const int* in_sizes, int n_in,
                              void* d_out, int out_size, void* d_ws, size_t ws_size,
                              hipStream_t stream) {
    const float* traffic  = (const float*)d_in[0];
    const float* packets  = (const float*)d_in[1];
    const float* tdp      = (const float*)d_in[2];
    const float* capacity = (const float*)d_in[3];
    const int* link_to_path = (const int*)d_in[4];
    const int* path_ids     = (const int*)d_in[5];
    const int* seq_path     = (const int*)d_in[6];
    const int* path_to_link = (const int*)d_in[7];
    const int* seq_links    = (const int*)d_in[8];
    const float* Wi_p = (const float*)d_in[11];
    const float* Wh_p = (const float*)d_in[12];
    const float* bi_p = (const float*)d_in[13];
    const float* bh_p = (const float*)d_in[14];
    const float* Wi_l = (const float*)d_in[15];
    const float* Wh_l = (const float*)d_in[16];
    const float* bi_l = (const float*)d_in[17];
    const float* bh_l = (const float*)d_in[18];
    const float* W1 = (const float*)d_in[19];
    const float* b1 = (const float*)d_in[20];
    const float* W2 = (const float*)d_in[21];
    const float* b2 = (const float*)d_in[22];
    const float* W3 = (const float*)d_in[23];
    const float* b3 = (const float*)d_in[24];
    float* out = (float*)d_out;

    float* path_state = (float*)d_ws;                  // NP*32 f32
    float* link_state = path_state + (size_t)NP * DD;  // NL*32
    float* w2t        = link_state + (size_t)NL * DD;  // 256*256
    int* lens     = (int*)(w2t + RUU * RUU);           // NP
    int* cnt      = lens + NP;                         // NL
    int* offs     = cnt + NL;                          // NL+1
    int* cursor   = offs + NL + 1;                     // NL
    int* csr_pids = cursor + NL;                       // NE

    k_init<<<(NP + 255) / 256, 256, 0, stream>>>(traffic, packets, tdp, capacity,
                                                 path_state, link_state, lens, cnt);
    k_lens<<<(NE + 255) / 256, 256, 0, stream>>>(path_ids, seq_path, lens);
    k_csr_count<<<(NE + 255) / 256, 256, 0, stream>>>(seq_links, cnt);
    k_csr_scan<<<1, 256, 0, stream>>>(cnt, offs, cursor);
    k_csr_fill<<<(NE + 255) / 256, 256, 0, stream>>>(seq_links, path_to_link,
                                                     cursor, csr_pids);
    k_w2t<<<RUU, RUU, 0, stream>>>(W2, w2t);
    for (int t = 0; t < TITERS; t++) {
        k_gru_paths<<<NP / PPB, 256, 0, stream>>>(
            link_state, path_state, link_to_path, lens, Wi_p, Wh_p, bi_p, bh_p);
        k_links<<<NL / LPB, 256, 0, stream>>>(
            path_state, link_state, offs, csr_pids, Wi_l, Wh_l, bi_l, bh_l);
    }
    k_readout<<<(NP + RPB - 1) / RPB, 256, 0, stream>>>(path_state, out, W1, b1,
                                                        w2t, b2, W3, b3);
}

// Round 17
// 1249.391 us; speedup vs baseline: 1.2588x; 1.2588x over previous
//
#include <hip/hip_runtime.h>

#define NP 50000
#define NL 10000
#define PLEN 5
#define NE (NP * PLEN)
#define DD 32
#define RUU 256
#define TITERS 8
#define PPB 16   /* paths per block (4 per wave) */
#define LPB 4    /* links per block (1 per wave) */
#define RPB 32   /* paths per readout block */

__device__ __forceinline__ float sigmoidf_(float a) {
    return 1.0f / (1.0f + __expf(-a));
}
__device__ __forceinline__ float tanhf_(float a) {
    a = fminf(fmaxf(a, -15.0f), 15.0f);
    float t = __expf(2.0f * a);
    return (t - 1.0f) / (t + 1.0f);
}

__global__ __launch_bounds__(256) void k_init(
    const float* __restrict__ traffic, const float* __restrict__ packets,
    const float* __restrict__ tdp, const float* __restrict__ capacity,
    float* __restrict__ path_state, float* __restrict__ link_state,
    int* __restrict__ lens, int* __restrict__ cnt) {
    int i = blockIdx.x * 256 + threadIdx.x;
    if (i < NP) {
        float v[DD];
        v[0] = traffic[i];
        v[1] = packets[i];
#pragma unroll
        for (int k = 0; k < 12; k++) v[2 + k] = tdp[i * 12 + k];
#pragma unroll
        for (int k = 14; k < DD; k++) v[k] = 0.0f;
#pragma unroll
        for (int k = 0; k < DD; k++) path_state[i * DD + k] = v[k];
        lens[i] = 0;
    }
    if (i < NL) {
        link_state[i * DD] = capacity[i];
#pragma unroll
        for (int k = 1; k < DD; k++) link_state[i * DD + k] = 0.0f;
        cnt[i] = 0;
    }
}

__global__ __launch_bounds__(256) void k_lens(const int* __restrict__ path_ids,
                                              const int* __restrict__ seq_path,
                                              int* __restrict__ lens) {
    int e = blockIdx.x * 256 + threadIdx.x;
    if (e < NE) atomicMax(&lens[path_ids[e]], seq_path[e] + 1);
}

__global__ __launch_bounds__(256) void k_csr_count(const int* __restrict__ seq_links,
                                                   int* __restrict__ cnt) {
    int e = blockIdx.x * 256 + threadIdx.x;
    if (e < NE) atomicAdd(&cnt[seq_links[e]], 1);
}

__global__ __launch_bounds__(256) void k_csr_scan(const int* __restrict__ cnt,
                                                  int* __restrict__ offs,
                                                  int* __restrict__ cursor) {
    __shared__ int ssum[256];
    const int tid = threadIdx.x;
    const int CH = 40;
    int base = tid * CH;
    int s = 0;
    for (int i = 0; i < CH; i++) {
        int idx = base + i;
        s += (idx < NL) ? cnt[idx] : 0;
    }
    ssum[tid] = s;
    __syncthreads();
    for (int off = 1; off < 256; off <<= 1) {
        int t = (tid >= off) ? ssum[tid - off] : 0;
        __syncthreads();
        ssum[tid] += t;
        __syncthreads();
    }
    int run = ssum[tid] - s;
    for (int i = 0; i < CH; i++) {
        int idx = base + i;
        if (idx < NL) {
            offs[idx] = run;
            cursor[idx] = run;
            run += cnt[idx];
        }
    }
    if (tid == 0) offs[NL] = ssum[255];
}

__global__ __launch_bounds__(256) void k_csr_fill(const int* __restrict__ seq_links,
                                                  const int* __restrict__ path_to_link,
                                                  int* __restrict__ cursor,
                                                  int* __restrict__ csr_pids) {
    int e = blockIdx.x * 256 + threadIdx.x;
    if (e < NE) {
        int l = seq_links[e];
        int slot = atomicAdd(&cursor[l], 1);
        csr_pids[slot] = path_to_link[e];
    }
}

__global__ __launch_bounds__(256) void k_w2t(const float* __restrict__ W2,
                                             float* __restrict__ W2t) {
    int j = blockIdx.x, k = threadIdx.x;
    W2t[k * RUU + j] = W2[j * RUU + k];
}

// Path GRU, phase-split. Phase 1: pipelined gather + Wi (round-12 proven).
// Phase 2: recurrence with Wh, 2 paths interleaved (round-16 proven, ~8us/iter).
__global__ __launch_bounds__(256, 4) void k_gru_paths(
    const float* __restrict__ link_state, float* __restrict__ path_state,
    const int* __restrict__ link_to_path, const int* __restrict__ lens,
    const float* __restrict__ Wi, const float* __restrict__ Wh,
    const float* __restrict__ bi, const float* __restrict__ bh) {
    __shared__ float gi[PPB * PLEN * 96];   // 30720 B
    __shared__ float hbuf[4][2][DD];        // 1 KB
    const int tid = threadIdx.x;
    const int wave = tid >> 6;
    const int lane = tid & 63;
    const int d = lane & 31;
    const int half = lane >> 5;
    const int pl0 = wave * 4;
    const int pbase = blockIdx.x * PPB;

    float w[3][16];
    // ---- Phase 1: input transform with Wi, pipelined gather ----
#pragma unroll
    for (int g = 0; g < 3; g++) {
        const float* wp = &Wi[(g * 32 + d) * 32 + half * 16];
#pragma unroll
        for (int c = 0; c < 4; c++) *(float4*)&w[g][c * 4] = *(const float4*)&wp[c * 4];
    }
#pragma unroll
    for (int g = 0; g < 3; g++)
#pragma unroll
        for (int k = 0; k < 16; k++) asm volatile("" : "+v"(w[g][k]));
    {
        const float b0 = bi[d], b1_ = bi[d + 32], b2_ = bi[d + 64];
        int lia[4 * PLEN];
#pragma unroll
        for (int j = 0; j < 4; j++) {
            const int p = pbase + pl0 + j;
#pragma unroll
            for (int s = 0; s < PLEN; s++) lia[j * PLEN + s] = link_to_path[p * PLEN + s];
        }
        float xk[16];
#pragma unroll
        for (int c = 0; c < 4; c++)
            *(float4*)&xk[c * 4] =
                *(const float4*)&link_state[lia[0] * DD + half * 16 + c * 4];
#pragma unroll
        for (int u = 0; u < 20; u++) {
            float xn[16];
            if (u + 1 < 20) {
#pragma unroll
                for (int c = 0; c < 4; c++)
                    *(float4*)&xn[c * 4] =
                        *(const float4*)&link_state[lia[u + 1] * DD + half * 16 + c * 4];
            }
            float s0 = 0.f, s1 = 0.f, s2 = 0.f;
#pragma unroll
            for (int k = 0; k < 16; k++) {
                s0 = fmaf(xk[k], w[0][k], s0);
                s1 = fmaf(xk[k], w[1][k], s1);
                s2 = fmaf(xk[k], w[2][k], s2);
            }
            s0 += __shfl_xor(s0, 32);
            s1 += __shfl_xor(s1, 32);
            s2 += __shfl_xor(s2, 32);
            float* gp = &gi[(pl0 + (u / 5)) * (PLEN * 96) + (u % 5) * 96];
            gp[d]      = s0 + b0;
            gp[d + 32] = s1 + b1_;
            gp[d + 64] = s2 + b2_;
            if (u + 1 < 20) {
#pragma unroll
                for (int k = 0; k < 16; k++) xk[k] = xn[k];
            }
        }
    }
    __syncthreads();   // phase fence

    // ---- Phase 2: recurrence with Wh (register reuse), 2 paths in flight ----
#pragma unroll
    for (int g = 0; g < 3; g++) {
        const float* wp = &Wh[(g * 32 + d) * 32 + half * 16];
#pragma unroll
        for (int c = 0; c < 4; c++) *(float4*)&w[g][c * 4] = *(const float4*)&wp[c * 4];
    }
#pragma unroll
    for (int g = 0; g < 3; g++)
#pragma unroll
        for (int k = 0; k < 16; k++) asm volatile("" : "+v"(w[g][k]));
    const float bh0 = bh[d], bh1 = bh[d + 32], bh2 = bh[d + 64];

    for (int j = 0; j < 4; j += 2) {
        const int pA = pbase + pl0 + j;
        const int pB = pA + 1;
        const int lenA = lens[pA], lenB = lens[pB];
        float hdA = path_state[pA * DD + d];
        float hdB = path_state[pB * DD + d];
        float hkA[16], hkB[16];
#pragma unroll
        for (int c = 0; c < 4; c++) {
            *(float4*)&hkA[c * 4] = *(const float4*)&path_state[pA * DD + half * 16 + c * 4];
            *(float4*)&hkB[c * 4] = *(const float4*)&path_state[pB * DD + half * 16 + c * 4];
        }
#pragma unroll
        for (int st = 0; st < PLEN; st++) {
            float hrA = 0.f, hzA = 0.f, hnA = 0.f;
            float hrB = 0.f, hzB = 0.f, hnB = 0.f;
#pragma unroll
            for (int k = 0; k < 16; k++) {
                hrA = fmaf(hkA[k], w[0][k], hrA);
                hzA = fmaf(hkA[k], w[1][k], hzA);
                hnA = fmaf(hkA[k], w[2][k], hnA);
                hrB = fmaf(hkB[k], w[0][k], hrB);
                hzB = fmaf(hkB[k], w[1][k], hzB);
                hnB = fmaf(hkB[k], w[2][k], hnB);
            }
            hrA += __shfl_xor(hrA, 32);
            hzA += __shfl_xor(hzA, 32);
            hnA += __shfl_xor(hnA, 32);
            hrB += __shfl_xor(hrB, 32);
            hzB += __shfl_xor(hzB, 32);
            hnB += __shfl_xor(hnB, 32);
            const float* gpA = &gi[((pl0 + j) * PLEN + st) * 96];
            const float* gpB = &gi[((pl0 + j + 1) * PLEN + st) * 96];
            float rA = sigmoidf_(gpA[d] + hrA + bh0);
            float zA = sigmoidf_(gpA[d + 32] + hzA + bh1);
            float nA = tanhf_(gpA[d + 64] + rA * (hnA + bh2));
            float rB = sigmoidf_(gpB[d] + hrB + bh0);
            float zB = sigmoidf_(gpB[d + 32] + hzB + bh1);
            float nB = tanhf_(gpB[d + 64] + rB * (hnB + bh2));
            float hnewA = (1.0f - zA) * nA + zA * hdA;
            float hnewB = (1.0f - zB) * nB + zB * hdB;
            hdA = (st < lenA) ? hnewA : hdA;
            hdB = (st < lenB) ? hnewB : hdB;
            hbuf[wave][0][d] = hdA;   // unconditional, identical bits both halves
            hbuf[wave][1][d] = hdB;
#pragma unroll
            for (int c = 0; c < 4; c++) {
                *(float4*)&hkA[c * 4] = *(const float4*)&hbuf[wave][0][half * 16 + c * 4];
                *(float4*)&hkB[c * 4] = *(const float4*)&hbuf[wave][1][half * 16 + c * 4];
            }
        }
        if (half == 0) {
            path_state[pA * DD + d] = hdA;
            path_state[pB * DD + d] = hdB;
        }
    }
}

// Link update, 3-phase; wave = 1 link; 4-deep pipelined gather (round-12).
__global__ __launch_bounds__(256, 4) void k_links(
    const float* __restrict__ path_state, float* __restrict__ link_state,
    const int* __restrict__ offs, const int* __restrict__ csr_pids,
    const float* __restrict__ Wi, const float* __restrict__ Wh,
    const float* __restrict__ bi, const float* __restrict__ bh) {
    __shared__ float xsum[4][DD];     // 512 B
    __shared__ float gil[4][96];      // 1536 B
    const int tid = threadIdx.x;
    const int wave = tid >> 6;
    const int lane = tid & 63;
    const int d = lane & 31;
    const int half = lane >> 5;
    const int l = blockIdx.x * LPB + wave;

    float w[3][16];
#pragma unroll
    for (int g = 0; g < 3; g++) {
        const float* wp = &Wi[(g * 32 + d) * 32 + half * 16];
#pragma unroll
        for (int c = 0; c < 4; c++) *(float4*)&w[g][c * 4] = *(const float4*)&wp[c * 4];
    }
#pragma unroll
    for (int g = 0; g < 3; g++)
#pragma unroll
        for (int k = 0; k < 16; k++) asm volatile("" : "+v"(w[g][k]));

    const int beg = offs[l], end = offs[l + 1];
    float a0 = 0.f, a1 = 0.f, a2 = 0.f, a3 = 0.f;
    int t = beg + half;
    for (; t + 6 < end; t += 8) {
        int q0 = csr_pids[t];
        int q1 = csr_pids[t + 2];
        int q2 = csr_pids[t + 4];
        int q3 = csr_pids[t + 6];
        a0 += path_state[q0 * DD + d];
        a1 += path_state[q1 * DD + d];
        a2 += path_state[q2 * DD + d];
        a3 += path_state[q3 * DD + d];
    }
    for (; t < end; t += 2) a0 += path_state[csr_pids[t] * DD + d];
    float xv = (a0 + a1) + (a2 + a3);
    xv += __shfl_xor(xv, 32);
    xsum[wave][d] = xv;
    __syncthreads();

    {
        const float b0 = bi[d], b1_ = bi[d + 32], b2_ = bi[d + 64];
        float xk[16];
#pragma unroll
        for (int c = 0; c < 4; c++)
            *(float4*)&xk[c * 4] = *(const float4*)&xsum[wave][half * 16 + c * 4];
        float s0 = 0.f, s1 = 0.f, s2 = 0.f;
#pragma unroll
        for (int k = 0; k < 16; k++) {
            s0 = fmaf(xk[k], w[0][k], s0);
            s1 = fmaf(xk[k], w[1][k], s1);
            s2 = fmaf(xk[k], w[2][k], s2);
        }
        s0 += __shfl_xor(s0, 32);
        s1 += __shfl_xor(s1, 32);
        s2 += __shfl_xor(s2, 32);
        gil[wave][d]      = s0 + b0;
        gil[wave][d + 32] = s1 + b1_;
        gil[wave][d + 64] = s2 + b2_;
    }
    __syncthreads();

#pragma unroll
    for (int g = 0; g < 3; g++) {
        const float* wp = &Wh[(g * 32 + d) * 32 + half * 16];
#pragma unroll
        for (int c = 0; c < 4; c++) *(float4*)&w[g][c * 4] = *(const float4*)&wp[c * 4];
    }
#pragma unroll
    for (int g = 0; g < 3; g++)
#pragma unroll
        for (int k = 0; k < 16; k++) asm volatile("" : "+v"(w[g][k]));
    const float bh0 = bh[d], bh1 = bh[d + 32], bh2 = bh[d + 64];
    {
        float hd = link_state[l * DD + d];
        float hk[16];
#pragma unroll
        for (int c = 0; c < 4; c++)
            *(float4*)&hk[c * 4] = *(const float4*)&link_state[l * DD + half * 16 + c * 4];
        float hr = 0.f, hz = 0.f, hn = 0.f;
#pragma unroll
        for (int k = 0; k < 16; k++) {
            hr = fmaf(hk[k], w[0][k], hr);
            hz = fmaf(hk[k], w[1][k], hz);
            hn = fmaf(hk[k], w[2][k], hn);
        }
        hr += __shfl_xor(hr, 32);
        hz += __shfl_xor(hz, 32);
        hn += __shfl_xor(hn, 32);
        float gir = gil[wave][d], giz = gil[wave][d + 32], gin = gil[wave][d + 64];
        float r = sigmoidf_(gir + hr + bh0);
        float z = sigmoidf_(giz + hz + bh1);
        float n = tanhf_(gin + r * (hn + bh2));
        float hnew = (1.0f - z) * n + z * hd;
        if (half == 0) link_state[l * DD + d] = hnew;
    }
}

// Readout: round-12 verbatim (proven 138us / 48 VGPR / no spill).
// 32 paths/block, LDS 32KB, thread tile 4x8, direct in-loop W2t loads.
__global__ __launch_bounds__(256, 4) void k_readout(
    const float* __restrict__ path_state, float* __restrict__ out,
    const float* __restrict__ W1, const float* __restrict__ b1,
    const float* __restrict__ W2t, const float* __restrict__ b2,
    const float* __restrict__ W3, const float* __restrict__ b3) {
    __shared__ float sr1[RPB * RUU];     // 32 KB
    const int tid = threadIdx.x;
    const int p0 = blockIdx.x * RPB;

    float w1r[DD];
#pragma unroll
    for (int c = 0; c < 8; c++)
        *(float4*)&w1r[c * 4] = *(const float4*)&W1[tid * DD + c * 4];
    float bb1 = b1[tid];

#pragma unroll 2
    for (int m = 0; m < RPB; m++) {
        int p = p0 + m;
        if (p >= NP) p = NP - 1;
        const float4* xr = (const float4*)&path_state[(size_t)p * DD];
        float acc = bb1;
#pragma unroll
        for (int c = 0; c < 8; c++) {
            float4 xv = xr[c];
            acc = fmaf(xv.x, w1r[c * 4 + 0], fmaf(xv.y, w1r[c * 4 + 1],
                  fmaf(xv.z, w1r[c * 4 + 2], fmaf(xv.w, w1r[c * 4 + 3], acc))));
        }
        sr1[m * RUU + tid] = fmaxf(acc, 0.0f);
    }
    __syncthreads();

    const int pig = tid >> 5;   // 8 groups x 4 paths
    const int jg  = tid & 31;   // 32 groups x 8 cols
    float accs[4][8];
#pragma unroll
    for (int jj = 0; jj < 8; jj++) {
        float bv = b2[jg * 8 + jj];
#pragma unroll
        for (int pp = 0; pp < 4; pp++) accs[pp][jj] = bv;
    }
    for (int k4 = 0; k4 < 64; k4++) {
        const int k0 = k4 * 4;
        float a[4][4];
#pragma unroll
        for (int pp = 0; pp < 4; pp++)
            *(float4*)&a[pp][0] = *(const float4*)&sr1[(pig * 4 + pp) * RUU + k0];
#pragma unroll
        for (int kk = 0; kk < 4; kk++) {
            float4 w0 = *(const float4*)&W2t[(size_t)(k0 + kk) * RUU + jg * 8];
            float4 w1_ = *(const float4*)&W2t[(size_t)(k0 + kk) * RUU + jg * 8 + 4];
#pragma unroll
            for (int pp = 0; pp < 4; pp++) {
                float av = a[pp][kk];
                accs[pp][0] = fmaf(av, w0.x, accs[pp][0]);
                accs[pp][1] = fmaf(av, w0.y, accs[pp][1]);
                accs[pp][2] = fmaf(av, w0.z, accs[pp][2]);
                accs[pp][3] = fmaf(av, w0.w, accs[pp][3]);
                accs[pp][4] = fmaf(av, w1_.x, accs[pp][4]);
                accs[pp][5] = fmaf(av, w1_.y, accs[pp][5]);
                accs[pp][6] = fmaf(av, w1_.z, accs[pp][6]);
                accs[pp][7] = fmaf(av, w1_.w, accs[pp][7]);
            }
        }
    }

    float w3r[8];
#pragma unroll
    for (int c = 0; c < 2; c++)
        *(float4*)&w3r[c * 4] = *(const float4*)&W3[jg * 8 + c * 4];
    float val[4];
#pragma unroll
    for (int pp = 0; pp < 4; pp++) {
        float v = 0.f;
#pragma unroll
        for (int jj = 0; jj < 8; jj++) v = fmaf(w3r[jj], fmaxf(accs[pp][jj], 0.f), v);
        val[pp] = v;
    }
#pragma unroll
    for (int m = 1; m < 32; m <<= 1)
#pragma unroll
        for (int pp = 0; pp < 4; pp++) val[pp] += __shfl_xor(val[pp], m);
    if (jg == 0) {
        float b3v = b3[0];
#pragma unroll
        for (int pp = 0; pp < 4; pp++) {
            int p = p0 + pig * 4 + pp;
            if (p < NP) out[p] = val[pp] + b3v;
        }
    }
}

extern "C" void kernel_launch(void* const* d_in, const int* in_sizes, int n_in,
                              void* d_out, int out_size, void* d_ws, size_t ws_size,
                              hipStream_t stream) {
    const float* traffic  = (const float*)d_in[0];
    const float* packets  = (const float*)d_in[1];
    const float* tdp      = (const float*)d_in[2];
    const float* capacity = (const float*)d_in[3];
    const int* link_to_path = (const int*)d_in[4];
    const int* path_ids     = (const int*)d_in[5];
    const int* seq_path     = (const int*)d_in[6];
    const int* path_to_link = (const int*)d_in[7];
    const int* seq_links    = (const int*)d_in[8];
    const float* Wi_p = (const float*)d_in[11];
    const float* Wh_p = (const float*)d_in[12];
    const float* bi_p = (const float*)d_in[13];
    const float* bh_p = (const float*)d_in[14];
    const float* Wi_l = (const float*)d_in[15];
    const float* Wh_l = (const float*)d_in[16];
    const float* bi_l = (const float*)d_in[17];
    const float* bh_l = (const float*)d_in[18];
    const float* W1 = (const float*)d_in[19];
    const float* b1 = (const float*)d_in[20];
    const float* W2 = (const float*)d_in[21];
    const float* b2 = (const float*)d_in[22];
    const float* W3 = (const float*)d_in[23];
    const float* b3 = (const float*)d_in[24];
    float* out = (float*)d_out;

    float* path_state = (float*)d_ws;                  // NP*32 f32
    float* link_state = path_state + (size_t)NP * DD;  // NL*32
    float* w2t        = link_state + (size_t)NL * DD;  // 256*256
    int* lens     = (int*)(w2t + RUU * RUU);           // NP
    int* cnt      = lens + NP;                         // NL
    int* offs     = cnt + NL;                          // NL+1
    int* cursor   = offs + NL + 1;                     // NL
    int* csr_pids = cursor + NL;                       // NE

    k_init<<<(NP + 255) / 256, 256, 0, stream>>>(traffic, packets, tdp, capacity,
                                                 path_state, link_state, lens, cnt);
    k_lens<<<(NE + 255) / 256, 256, 0, stream>>>(path_ids, seq_path, lens);
    k_csr_count<<<(NE + 255) / 256, 256, 0, stream>>>(seq_links, cnt);
    k_csr_scan<<<1, 256, 0, stream>>>(cnt, offs, cursor);
    k_csr_fill<<<(NE + 255) / 256, 256, 0, stream>>>(seq_links, path_to_link,
                                                     cursor, csr_pids);
    k_w2t<<<RUU, RUU, 0, stream>>>(W2, w2t);
    for (int t = 0; t < TITERS; t++) {
        k_gru_paths<<<NP / PPB, 256, 0, stream>>>(
            link_state, path_state, link_to_path, lens, Wi_p, Wh_p, bi_p, bh_p);
        k_links<<<NL / LPB, 256, 0, stream>>>(
            path_state, link_state, offs, csr_pids, Wi_l, Wh_l, bi_l, bh_l);
    }
    k_readout<<<(NP + RPB - 1) / RPB, 256, 0, stream>>>(path_state, out, W1, b1,
                                                        w2t, b2, W3, b3);
}